// Round 13
// baseline (322.705 us; speedup 1.0000x reference)
//
#include <hip/hip_runtime.h>
#include <math.h>

#define B_ 8
#define P_ 1024
#define N_ 32
#define L_ 125
#define H_ 256
#define E_ 128
#define MT 64             // points per block; 8 waves, wave w owns j in [32w,32w+32)

static_assert(E_ == 3 + L_, "embed dim mismatch");

typedef _Float16 half8 __attribute__((ext_vector_type(8)));
typedef _Float16 half4v __attribute__((ext_vector_type(4)));
typedef float f32x16 __attribute__((ext_vector_type(16)));

// ---------------------------------------------------------------------------
// prep: fused Z-precompute (blocks 0..255) + W transpose/split (blocks 256..1279).
//   Z[b][n][j] = b0[n][j] + sum_l latents[n][b][l] * W0[n][3+l][j]   (plain store)
//   WT[layer][node] in MFMA fragment order [w(8)][kc(16)][kh(2)][lc(32)][8]
// ---------------------------------------------------------------------------
__global__ void prep(const float* __restrict__ latents,
                     const float* __restrict__ W0,
                     const float* __restrict__ b0,
                     const float* __restrict__ W1,
                     const float* __restrict__ W2,
                     float* __restrict__ Z,
                     _Float16* __restrict__ WThi,
                     _Float16* __restrict__ WTlo) {
  const int bid = blockIdx.x;
  const int t = threadIdx.x;            // 256
  if (bid < N_ * B_) {
    __shared__ float lat[L_];
    const int n = bid >> 3, b = bid & 7;
    if (t < L_) lat[t] = latents[(n * B_ + b) * L_ + t];
    __syncthreads();
    const float* w0 = W0 + ((size_t)n * E_ + 3) * H_ + t;
    float acc = b0[n * H_ + t];
#pragma unroll 5
    for (int l = 0; l < L_; ++l)
      acc = fmaf(lat[l], w0[(size_t)l * H_], acc);
    Z[(b * N_ + n) * H_ + t] = acc;
  } else {
    const int id = bid - N_ * B_;
    const int node = id >> 5;
    const int layer = (id >> 4) & 1;
    const int jb = (id >> 2) & 3;       // 64-wide j slice
    const int kb = id & 3;              // 64-wide k slice
    const float* W = (layer == 0 ? W1 : W2) + (size_t)node * H_ * H_;
    _Float16* dhi = WThi + ((size_t)layer * N_ + node) * H_ * H_;
    _Float16* dlo = WTlo + ((size_t)layer * N_ + node) * H_ * H_;
    __shared__ float tile[64][65];      // [k][j]
    {
      const int col = t & 63;
#pragma unroll
      for (int i = 0; i < 16; ++i) {
        const int row = (t >> 6) * 16 + i;
        tile[row][col] = W[(size_t)(kb * 64 + row) * H_ + jb * 64 + col];
      }
    }
    __syncthreads();
    const int j_l = t >> 2;             // 0..63
    const int j = jb * 64 + j_l;
    const int w = j >> 5, lc = j & 31;
    const int kq = (t & 3) * 16;        // 16 consecutive k = one kc (kh 0+1)
    const int kc = kb * 4 + (t & 3);
    half8 hv0, hv1, lv0, lv1;
#pragma unroll
    for (int q = 0; q < 16; ++q) {
      const float v = tile[kq + q][j_l];
      const _Float16 hh = (_Float16)v;
      const _Float16 ll = (_Float16)(v - (float)hh);
      if (q < 8) { hv0[q] = hh; lv0[q] = ll; }
      else       { hv1[q - 8] = hh; lv1[q - 8] = ll; }
    }
    const size_t o0 = (size_t)w * 8192 + (size_t)kc * 512 + lc * 8;  // kh=0
    const size_t o1 = o0 + 256;                                       // kh=1
    *(half8*)(dhi + o0) = hv0;
    *(half8*)(dhi + o1) = hv1;
    *(half8*)(dlo + o0) = lv0;
    *(half8*)(dlo + o1) = lv1;
  }
}

// ---------------------------------------------------------------------------
// Main fused kernel. 4096 blocks; (node, ptile) XCD-aware decode.
// Block = 64 points x 1 node, 512 thr = 8 waves; wave w owns j in [32w,32w+32),
// computes C^T[32j x 64m] = 2 x 32x32 tiles via 32x32x16 f16 MFMA, 3-term split.
// Pipeline: A 3-slot rotation (kc..kc+2, global/L2), B 2-slot rotation (LDS),
// hand-unrolled 16 steps, named registers.
// LAUNCH BOUNDS NOTE (r12 post-mortem): with 512-thr blocks hipcc maps the 2nd
// arg empirically as blocks/CU: arg=4 -> 64-VGPR cap (r11/r12 spilled 113 MB to
// scratch); arg=2 -> 128-VGPR cap (r5=128, r8=88). Pipeline needs ~110 VGPR, so
// (512,2). Occupancy unchanged: LDS 66 KB already limits to 2 blocks/CU.
// ---------------------------------------------------------------------------
__global__ __launch_bounds__(512, 2)
void mlp_main(const float* __restrict__ X,
              const float* __restrict__ constants,
              const float* __restrict__ scales,
              const float* __restrict__ rotations,
              const float* __restrict__ centers,
              const float* __restrict__ W0,
              const float* __restrict__ b1,
              const float* __restrict__ b2,
              const float* __restrict__ Wout,
              const float* __restrict__ bout,
              const float* __restrict__ Z,
              const _Float16* __restrict__ WThi,
              const _Float16* __restrict__ WTlo,
              const int* __restrict__ use_constants,
              float* __restrict__ pred) {
  __shared__ _Float16 h_hi[MT * H_];   // 32 KB
  __shared__ _Float16 h_lo[MT * H_];   // 32 KB
  __shared__ float loc[MT][3];
  __shared__ float wgt[MT];
  __shared__ float predpart[MT];

  const int ell = blockIdx.x;
  const int node = (ell & 7) * 4 + ((ell >> 3) & 3);  // xcd*4 + q
  const int p0 = (ell >> 5) * MT;       // 128 ptiles
  const int b = p0 >> 10;               // P_ == 1024
  const int tid = threadIdx.x;
  const int lane = tid & 63;
  const int w = tid >> 6;
  const int lc = lane & 31;
  const int kh = lane >> 5;

  if (tid < MT) {
    predpart[tid] = 0.f;
    const int pidx = p0 + tid;
    const float x0 = X[pidx * 3 + 0];
    const float x1 = X[pidx * 3 + 1];
    const float x2 = X[pidx * 3 + 2];
    const float* R = rotations + (size_t)(b * N_ + node) * 9;
    const float* C = centers + (size_t)(b * N_ + node) * 3;
    const float* S = scales + (size_t)(b * N_ + node) * 3;
    const float d0 = x0 - C[0], d1 = x1 - C[1], d2 = x2 - C[2];
    const float l0 = (R[0] * d0 + R[1] * d1 + R[2] * d2) / S[0];
    const float l1 = (R[3] * d0 + R[4] * d1 + R[5] * d2) / S[1];
    const float l2 = (R[6] * d0 + R[7] * d1 + R[8] * d2) / S[2];
    loc[tid][0] = l0; loc[tid][1] = l1; loc[tid][2] = l2;
    float ww = expf(-0.5f * (l0 * l0 + l1 * l1 + l2 * l2));
    if (use_constants[0] != 0) ww *= constants[b * N_ + node];
    wgt[tid] = ww;
  }
  __syncthreads();

  // ---- layer 0: lane owns point m=lane; wave w covers j in [32w,32w+32).
  {
    const int m = lane;
    const float l0 = loc[m][0], l1 = loc[m][1], l2 = loc[m][2];
    const float* w0p = W0 + (size_t)node * E_ * H_;
    const float* zp = Z + (size_t)(b * N_ + node) * H_;
    char* hhp = (char*)h_hi + m * 512;
    char* hlp = (char*)h_lo + m * 512;
    const int mx = m & 31;
#pragma unroll
    for (int j = w * 32; j < w * 32 + 32; j += 4) {
      const float4 a0 = *(const float4*)(w0p + j);
      const float4 a1 = *(const float4*)(w0p + H_ + j);
      const float4 a2 = *(const float4*)(w0p + 2 * H_ + j);
      const float4 zz = *(const float4*)(zp + j);
      float v[4];
      v[0] = fmaxf(fmaf(l2, a2.x, fmaf(l1, a1.x, fmaf(l0, a0.x, zz.x))), 0.f);
      v[1] = fmaxf(fmaf(l2, a2.y, fmaf(l1, a1.y, fmaf(l0, a0.y, zz.y))), 0.f);
      v[2] = fmaxf(fmaf(l2, a2.z, fmaf(l1, a1.z, fmaf(l0, a0.z, zz.z))), 0.f);
      v[3] = fmaxf(fmaf(l2, a2.w, fmaf(l1, a1.w, fmaf(l0, a0.w, zz.w))), 0.f);
      half4v hv, lv;
#pragma unroll
      for (int r = 0; r < 4; ++r) {
        const _Float16 h16 = (_Float16)v[r];
        hv[r] = h16;
        lv[r] = (_Float16)(v[r] - (float)h16);
      }
      const int off = (((j >> 3) ^ mx) << 4) + ((j & 7) << 1);
      *(half4v*)(hhp + off) = hv;
      *(half4v*)(hlp + off) = lv;
    }
  }
  __syncthreads();

  f32x16 acc0, acc1;   // m 0..31 / m 32..63

  const size_t wb = (size_t)node * H_ * H_ + (size_t)w * 8192 + (kh * 32 + lc) * 8;
  const _Float16* wt1hi = WThi + wb;
  const _Float16* wt1lo = WTlo + wb;
  const _Float16* wt2hi = WThi + (size_t)N_ * H_ * H_ + wb;
  const _Float16* wt2lo = WTlo + (size_t)N_ * H_ * H_ + wb;

  const char* rbh0 = (const char*)h_hi + lc * 512;
  const char* rbh1 = (const char*)h_hi + (32 + lc) * 512;
  const char* rbl0 = (const char*)h_lo + lc * 512;
  const char* rbl1 = (const char*)h_lo + (32 + lc) * 512;

// A slot load (global/L2, 1024 B stride per kc)
#define LDA(AH, AL, K) \
  AH = *(const half8*)(wh + (K) * 512); \
  AL = *(const half8*)(wl + (K) * 512);
// B slot load (LDS, swizzled)
#define LDB(B0, B1, B2, B3, K) { \
  const int so_ = ((2 * (K) + kh) ^ lc) << 4; \
  B0 = *(const half8*)(rbh0 + so_); \
  B1 = *(const half8*)(rbh1 + so_); \
  B2 = *(const half8*)(rbl0 + so_); \
  B3 = *(const half8*)(rbl1 + so_); }
// 6-MFMA cluster, two interleaved acc chains
#define MM(AH, AL, B0, B1, B2, B3) \
  __builtin_amdgcn_s_setprio(1); \
  acc0 = __builtin_amdgcn_mfma_f32_32x32x16_f16(AH, B0, acc0, 0, 0, 0); \
  acc1 = __builtin_amdgcn_mfma_f32_32x32x16_f16(AH, B1, acc1, 0, 0, 0); \
  acc0 = __builtin_amdgcn_mfma_f32_32x32x16_f16(AH, B2, acc0, 0, 0, 0); \
  acc1 = __builtin_amdgcn_mfma_f32_32x32x16_f16(AH, B3, acc1, 0, 0, 0); \
  acc0 = __builtin_amdgcn_mfma_f32_32x32x16_f16(AL, B0, acc0, 0, 0, 0); \
  acc1 = __builtin_amdgcn_mfma_f32_32x32x16_f16(AL, B1, acc1, 0, 0, 0); \
  __builtin_amdgcn_s_setprio(0);

  auto run_layer = [&](const _Float16* __restrict__ wh,
                       const _Float16* __restrict__ wl) {
    acc0 = (f32x16)(0.f);
    acc1 = (f32x16)(0.f);
    // A rotation slots: hold kc, kc+1, kc+2. B rotation slots: kc, kc+1.
    half8 A0H, A0L, A1H, A1L, A2H, A2L;
    half8 S0B0, S0B1, S0B2, S0B3, S1B0, S1B1, S1B2, S1B3;
    LDA(A0H, A0L, 0)
    LDA(A1H, A1L, 1)
    LDB(S0B0, S0B1, S0B2, S0B3, 0)
    // step k: use A[k%3], B[k%2]; load A(k+2)->[(k+2)%3], B(k+1)->[(k+1)%2]
    LDA(A2H, A2L, 2)  LDB(S1B0, S1B1, S1B2, S1B3, 1)  MM(A0H, A0L, S0B0, S0B1, S0B2, S0B3)   // 0
    LDA(A0H, A0L, 3)  LDB(S0B0, S0B1, S0B2, S0B3, 2)  MM(A1H, A1L, S1B0, S1B1, S1B2, S1B3)   // 1
    LDA(A1H, A1L, 4)  LDB(S1B0, S1B1, S1B2, S1B3, 3)  MM(A2H, A2L, S0B0, S0B1, S0B2, S0B3)   // 2
    LDA(A2H, A2L, 5)  LDB(S0B0, S0B1, S0B2, S0B3, 4)  MM(A0H, A0L, S1B0, S1B1, S1B2, S1B3)   // 3
    LDA(A0H, A0L, 6)  LDB(S1B0, S1B1, S1B2, S1B3, 5)  MM(A1H, A1L, S0B0, S0B1, S0B2, S0B3)   // 4
    LDA(A1H, A1L, 7)  LDB(S0B0, S0B1, S0B2, S0B3, 6)  MM(A2H, A2L, S1B0, S1B1, S1B2, S1B3)   // 5
    LDA(A2H, A2L, 8)  LDB(S1B0, S1B1, S1B2, S1B3, 7)  MM(A0H, A0L, S0B0, S0B1, S0B2, S0B3)   // 6
    LDA(A0H, A0L, 9)  LDB(S0B0, S0B1, S0B2, S0B3, 8)  MM(A1H, A1L, S1B0, S1B1, S1B2, S1B3)   // 7
    LDA(A1H, A1L, 10) LDB(S1B0, S1B1, S1B2, S1B3, 9)  MM(A2H, A2L, S0B0, S0B1, S0B2, S0B3)   // 8
    LDA(A2H, A2L, 11) LDB(S0B0, S0B1, S0B2, S0B3, 10) MM(A0H, A0L, S1B0, S1B1, S1B2, S1B3)   // 9
    LDA(A0H, A0L, 12) LDB(S1B0, S1B1, S1B2, S1B3, 11) MM(A1H, A1L, S0B0, S0B1, S0B2, S0B3)   // 10
    LDA(A1H, A1L, 13) LDB(S0B0, S0B1, S0B2, S0B3, 12) MM(A2H, A2L, S1B0, S1B1, S1B2, S1B3)   // 11
    LDA(A2H, A2L, 14) LDB(S1B0, S1B1, S1B2, S1B3, 13) MM(A0H, A0L, S0B0, S0B1, S0B2, S0B3)   // 12
    LDA(A0H, A0L, 15) LDB(S0B0, S0B1, S0B2, S0B3, 14) MM(A1H, A1L, S1B0, S1B1, S1B2, S1B3)   // 13
                      LDB(S1B0, S1B1, S1B2, S1B3, 15) MM(A2H, A2L, S0B0, S0B1, S0B2, S0B3)   // 14
                                                      MM(A0H, A0L, S1B0, S1B1, S1B2, S1B3)   // 15
  };

  // ---- layer 1 ----
  run_layer(wt1hi, wt1lo);
  __syncthreads();   // all waves done reading h0
  {
#pragma unroll
    for (int q = 0; q < 4; ++q) {
      const int jq = 32 * w + 8 * q + 4 * kh;
      const float4 bb = *(const float4*)(b1 + node * H_ + jq);
      const float bv[4] = {bb.x, bb.y, bb.z, bb.w};
      const int soff = ((((4 * w + q) ^ lc) << 4) + (kh << 3));
      half4v hv, lv;
#pragma unroll
      for (int r = 0; r < 4; ++r) {
        const float v = fmaxf(acc0[4 * q + r] + bv[r], 0.f);
        const _Float16 h16 = (_Float16)v;
        hv[r] = h16;
        lv[r] = (_Float16)(v - (float)h16);
      }
      *(half4v*)((char*)h_hi + lc * 512 + soff) = hv;
      *(half4v*)((char*)h_lo + lc * 512 + soff) = lv;
#pragma unroll
      for (int r = 0; r < 4; ++r) {
        const float v = fmaxf(acc1[4 * q + r] + bv[r], 0.f);
        const _Float16 h16 = (_Float16)v;
        hv[r] = h16;
        lv[r] = (_Float16)(v - (float)h16);
      }
      *(half4v*)((char*)h_hi + (32 + lc) * 512 + soff) = hv;
      *(half4v*)((char*)h_lo + (32 + lc) * 512 + soff) = lv;
    }
  }
  __syncthreads();

  // ---- layer 2 + fused Wout ----
  run_layer(wt2hi, wt2lo);
  {
    float s0 = 0.f, s1 = 0.f;
#pragma unroll
    for (int q = 0; q < 4; ++q) {
      const int jq = 32 * w + 8 * q + 4 * kh;
      const float4 bb = *(const float4*)(b2 + node * H_ + jq);
      const float4 wo = *(const float4*)(Wout + node * H_ + jq);
      const float bv[4] = {bb.x, bb.y, bb.z, bb.w};
      const float wv[4] = {wo.x, wo.y, wo.z, wo.w};
#pragma unroll
      for (int r = 0; r < 4; ++r) {
        s0 = fmaf(fmaxf(acc0[4 * q + r] + bv[r], 0.f), wv[r], s0);
        s1 = fmaf(fmaxf(acc1[4 * q + r] + bv[r], 0.f), wv[r], s1);
      }
    }
    s0 += __shfl_xor(s0, 32, 64);   // combine kh halves (same m)
    s1 += __shfl_xor(s1, 32, 64);
    if (lane < 32) {
      atomicAdd(&predpart[lc], s0);
      atomicAdd(&predpart[32 + lc], s1);
    }
  }
  __syncthreads();

  if (tid < MT)
    pred[(size_t)node * (B_ * P_) + p0 + tid] =
        wgt[tid] * (predpart[tid] + bout[node] + 0.5f);
}

// ---------------------------------------------------------------------------
// finalize: ldif = sum over nodes of pred[n][point]; sigmoid output.
// ---------------------------------------------------------------------------
__global__ void finalize(const float* __restrict__ pred, float* __restrict__ out) {
  const int i = blockIdx.x * 256 + threadIdx.x;
  float v = 0.f;
#pragma unroll
  for (int n = 0; n < N_; ++n) v += pred[n * (B_ * P_) + i];
  out[i] = v;
  const float zz = 100.0f * (-0.07f - v);
  out[B_ * P_ + i] = 1.0f / (1.0f + expf(-zz));
}

// ---------------------------------------------------------------------------
extern "C" void kernel_launch(void* const* d_in, const int* in_sizes, int n_in,
                              void* d_out, int out_size, void* d_ws, size_t ws_size,
                              hipStream_t stream) {
  const float* X = (const float*)d_in[0];
  const float* latents = (const float*)d_in[1];
  const float* constants = (const float*)d_in[2];
  const float* scales = (const float*)d_in[3];
  const float* rotations = (const float*)d_in[4];
  const float* centers = (const float*)d_in[5];
  const float* W0 = (const float*)d_in[6];
  const float* b0 = (const float*)d_in[7];
  const float* W1 = (const float*)d_in[8];
  const float* b1 = (const float*)d_in[9];
  const float* W2 = (const float*)d_in[10];
  const float* b2 = (const float*)d_in[11];
  const float* Wout = (const float*)d_in[12];
  const float* bout = (const float*)d_in[13];
  const int* use_constants = (const int*)d_in[14];

  float* pred = (float*)d_ws;                        // N*B*P f32 (1 MB)
  float* Zbuf = pred + (size_t)N_ * B_ * P_;         // B*N*H f32 (256 KB)
  _Float16* WThi = (_Float16*)(Zbuf + B_ * N_ * H_); // 8 MB
  _Float16* WTlo = WThi + (size_t)2 * N_ * H_ * H_;  // 8 MB

  prep<<<dim3(N_ * B_ + N_ * 2 * 16), 256, 0, stream>>>(
      latents, W0, b0, W1, W2, Zbuf, WThi, WTlo);

  mlp_main<<<dim3(B_ * P_ / MT * N_), 512, 0, stream>>>(
      X, constants, scales, rotations, centers, W0, b1, b2, Wout, bout,
      Zbuf, WThi, WTlo, use_constants, pred);

  finalize<<<dim3(B_ * P_ / 256), 256, 0, stream>>>(pred, (float*)d_out);
}

// Round 14
// 288.571 us; speedup vs baseline: 1.1183x; 1.1183x over previous
//
#include <hip/hip_runtime.h>
#include <math.h>

#define B_ 8
#define P_ 1024
#define N_ 32
#define L_ 125
#define H_ 256
#define E_ 128
#define MT 64             // points per block; 4 waves, wave w owns j in [64w,64w+64)

static_assert(E_ == 3 + L_, "embed dim mismatch");

typedef _Float16 half8 __attribute__((ext_vector_type(8)));
typedef _Float16 half4v __attribute__((ext_vector_type(4)));
typedef float f32x16 __attribute__((ext_vector_type(16)));

// ---------------------------------------------------------------------------
// prep: fused Z-precompute (blocks 0..255) + W transpose/split (blocks 256..1279).
//   Z[b][n][j] = b0[n][j] + sum_l latents[n][b][l] * W0[n][3+l][j]   (plain store)
//   WT[layer][node] in MFMA fragment order [jg(8)][kc(16)][kh(2)][lc(32)][8]
// ---------------------------------------------------------------------------
__global__ void prep(const float* __restrict__ latents,
                     const float* __restrict__ W0,
                     const float* __restrict__ b0,
                     const float* __restrict__ W1,
                     const float* __restrict__ W2,
                     float* __restrict__ Z,
                     _Float16* __restrict__ WThi,
                     _Float16* __restrict__ WTlo) {
  const int bid = blockIdx.x;
  const int t = threadIdx.x;            // 256
  if (bid < N_ * B_) {
    __shared__ float lat[L_];
    const int n = bid >> 3, b = bid & 7;
    if (t < L_) lat[t] = latents[(n * B_ + b) * L_ + t];
    __syncthreads();
    const float* w0 = W0 + ((size_t)n * E_ + 3) * H_ + t;
    float acc = b0[n * H_ + t];
#pragma unroll 5
    for (int l = 0; l < L_; ++l)
      acc = fmaf(lat[l], w0[(size_t)l * H_], acc);
    Z[(b * N_ + n) * H_ + t] = acc;
  } else {
    const int id = bid - N_ * B_;
    const int node = id >> 5;
    const int layer = (id >> 4) & 1;
    const int jb = (id >> 2) & 3;       // 64-wide j slice
    const int kb = id & 3;              // 64-wide k slice
    const float* W = (layer == 0 ? W1 : W2) + (size_t)node * H_ * H_;
    _Float16* dhi = WThi + ((size_t)layer * N_ + node) * H_ * H_;
    _Float16* dlo = WTlo + ((size_t)layer * N_ + node) * H_ * H_;
    __shared__ float tile[64][65];      // [k][j]
    {
      const int col = t & 63;
#pragma unroll
      for (int i = 0; i < 16; ++i) {
        const int row = (t >> 6) * 16 + i;
        tile[row][col] = W[(size_t)(kb * 64 + row) * H_ + jb * 64 + col];
      }
    }
    __syncthreads();
    const int j_l = t >> 2;             // 0..63
    const int j = jb * 64 + j_l;
    const int jg = j >> 5, lc = j & 31;
    const int kq = (t & 3) * 16;        // 16 consecutive k = one kc (kh 0+1)
    const int kc = kb * 4 + (t & 3);
    half8 hv0, hv1, lv0, lv1;
#pragma unroll
    for (int q = 0; q < 16; ++q) {
      const float v = tile[kq + q][j_l];
      const _Float16 hh = (_Float16)v;
      const _Float16 ll = (_Float16)(v - (float)hh);
      if (q < 8) { hv0[q] = hh; lv0[q] = ll; }
      else       { hv1[q - 8] = hh; lv1[q - 8] = ll; }
    }
    const size_t o0 = (size_t)jg * 8192 + (size_t)kc * 512 + lc * 8;  // kh=0
    const size_t o1 = o0 + 256;                                        // kh=1
    *(half8*)(dhi + o0) = hv0;
    *(half8*)(dhi + o1) = hv1;
    *(half8*)(dlo + o0) = lv0;
    *(half8*)(dlo + o1) = lv1;
  }
}

// ---------------------------------------------------------------------------
// Main fused kernel. 4096 blocks; (node, ptile) XCD-aware decode.
// Block = 64 points x 1 node, 256 thr = 4 waves; wave w owns j in [64w,64w+64)
// x all 64 m: 2x2 32x32 tiles, 12-MFMA clusters, 4 interleaved acc chains.
// Rationale (r13 post-mortem): hipcc launch_bounds(512,N) = N/2 blocks/CU for
// 512-thr blocks -> {4 waves/SIMD, 64 VGPR cap} XOR {2 waves/SIMD, 128 cap}.
// 256-thr blocks with (256,4) give 128-VGPR cap AND LDS-limited 2 blocks/CU
// (8 waves/CU). jt=2 halves LDS-read pressure per MFMA (r9 model: LDS pipe
// 197K cyc/CU == MFMA 198K -> co-bottleneck; now ~98K).
// A+B 1-deep named-register prefetch. Output: plain store pred[node][point].
// ---------------------------------------------------------------------------
__global__ __launch_bounds__(256, 4)
void mlp_main(const float* __restrict__ X,
              const float* __restrict__ constants,
              const float* __restrict__ scales,
              const float* __restrict__ rotations,
              const float* __restrict__ centers,
              const float* __restrict__ W0,
              const float* __restrict__ b1,
              const float* __restrict__ b2,
              const float* __restrict__ Wout,
              const float* __restrict__ bout,
              const float* __restrict__ Z,
              const _Float16* __restrict__ WThi,
              const _Float16* __restrict__ WTlo,
              const int* __restrict__ use_constants,
              float* __restrict__ pred) {
  __shared__ _Float16 h_hi[MT * H_];   // 32 KB
  __shared__ _Float16 h_lo[MT * H_];   // 32 KB
  __shared__ float loc[MT][3];
  __shared__ float wgt[MT];
  __shared__ float predpart[MT];

  const int ell = blockIdx.x;
  const int node = (ell & 7) * 4 + ((ell >> 3) & 3);  // xcd*4 + q
  const int p0 = (ell >> 5) * MT;       // 128 ptiles
  const int b = p0 >> 10;               // P_ == 1024
  const int tid = threadIdx.x;
  const int lane = tid & 63;
  const int w = tid >> 6;               // wave 0..3
  const int lc = lane & 31;
  const int kh = lane >> 5;

  if (tid < MT) {
    predpart[tid] = 0.f;
    const int pidx = p0 + tid;
    const float x0 = X[pidx * 3 + 0];
    const float x1 = X[pidx * 3 + 1];
    const float x2 = X[pidx * 3 + 2];
    const float* R = rotations + (size_t)(b * N_ + node) * 9;
    const float* C = centers + (size_t)(b * N_ + node) * 3;
    const float* S = scales + (size_t)(b * N_ + node) * 3;
    const float d0 = x0 - C[0], d1 = x1 - C[1], d2 = x2 - C[2];
    const float l0 = (R[0] * d0 + R[1] * d1 + R[2] * d2) / S[0];
    const float l1 = (R[3] * d0 + R[4] * d1 + R[5] * d2) / S[1];
    const float l2 = (R[6] * d0 + R[7] * d1 + R[8] * d2) / S[2];
    loc[tid][0] = l0; loc[tid][1] = l1; loc[tid][2] = l2;
    float ww = expf(-0.5f * (l0 * l0 + l1 * l1 + l2 * l2));
    if (use_constants[0] != 0) ww *= constants[b * N_ + node];
    wgt[tid] = ww;
  }
  __syncthreads();

  // ---- layer 0: thread owns point m = tid&63, j-range (tid>>6)*64 .. +64.
  {
    const int m = tid & 63;
    const int jr = (tid >> 6) * 64;
    const float l0 = loc[m][0], l1 = loc[m][1], l2 = loc[m][2];
    const float* w0p = W0 + (size_t)node * E_ * H_;
    const float* zp = Z + (size_t)(b * N_ + node) * H_;
    char* hhp = (char*)h_hi + m * 512;
    char* hlp = (char*)h_lo + m * 512;
    const int mx = m & 31;
#pragma unroll
    for (int j = jr; j < jr + 64; j += 4) {
      const float4 a0 = *(const float4*)(w0p + j);
      const float4 a1 = *(const float4*)(w0p + H_ + j);
      const float4 a2 = *(const float4*)(w0p + 2 * H_ + j);
      const float4 zz = *(const float4*)(zp + j);
      float v[4];
      v[0] = fmaxf(fmaf(l2, a2.x, fmaf(l1, a1.x, fmaf(l0, a0.x, zz.x))), 0.f);
      v[1] = fmaxf(fmaf(l2, a2.y, fmaf(l1, a1.y, fmaf(l0, a0.y, zz.y))), 0.f);
      v[2] = fmaxf(fmaf(l2, a2.z, fmaf(l1, a1.z, fmaf(l0, a0.z, zz.z))), 0.f);
      v[3] = fmaxf(fmaf(l2, a2.w, fmaf(l1, a1.w, fmaf(l0, a0.w, zz.w))), 0.f);
      half4v hv, lv;
#pragma unroll
      for (int r = 0; r < 4; ++r) {
        const _Float16 h16 = (_Float16)v[r];
        hv[r] = h16;
        lv[r] = (_Float16)(v[r] - (float)h16);
      }
      const int off = (((j >> 3) ^ mx) << 4) + ((j & 7) << 1);
      *(half4v*)(hhp + off) = hv;
      *(half4v*)(hlp + off) = lv;
    }
  }
  __syncthreads();

  f32x16 acc00, acc01, acc10, acc11;   // [jt][mt]

  // A base: jg = 2w (jt0) and 2w+1 (jt1), stride 8192 halves per jg.
  const size_t wb = (size_t)node * H_ * H_ + (size_t)(2 * w) * 8192 + (kh * 32 + lc) * 8;
  const _Float16* wt1hi = WThi + wb;
  const _Float16* wt1lo = WTlo + wb;
  const _Float16* wt2hi = WThi + (size_t)N_ * H_ * H_ + wb;
  const _Float16* wt2lo = WTlo + (size_t)N_ * H_ * H_ + wb;

  const char* rbh0 = (const char*)h_hi + lc * 512;
  const char* rbh1 = (const char*)h_hi + (32 + lc) * 512;
  const char* rbl0 = (const char*)h_lo + lc * 512;
  const char* rbl1 = (const char*)h_lo + (32 + lc) * 512;

// A slot load: jt0 (jg=2w) and jt1 (jg=2w+1), hi+lo
#define LDA(H0, L0, H1, L1, K) \
  H0 = *(const half8*)(wh + (K) * 512); \
  L0 = *(const half8*)(wl + (K) * 512); \
  H1 = *(const half8*)(wh + 8192 + (K) * 512); \
  L1 = *(const half8*)(wl + 8192 + (K) * 512);
// B slot load (LDS, swizzled): m0/m1 tiles, hi+lo
#define LDB(B0, B1, B2, B3, K) { \
  const int so_ = ((2 * (K) + kh) ^ lc) << 4; \
  B0 = *(const half8*)(rbh0 + so_); \
  B1 = *(const half8*)(rbh1 + so_); \
  B2 = *(const half8*)(rbl0 + so_); \
  B3 = *(const half8*)(rbl1 + so_); }
// 12-MFMA cluster, 4 interleaved acc chains
#define MM(H0, L0, H1, L1, B0, B1, B2, B3) \
  __builtin_amdgcn_s_setprio(1); \
  acc00 = __builtin_amdgcn_mfma_f32_32x32x16_f16(H0, B0, acc00, 0, 0, 0); \
  acc01 = __builtin_amdgcn_mfma_f32_32x32x16_f16(H0, B1, acc01, 0, 0, 0); \
  acc10 = __builtin_amdgcn_mfma_f32_32x32x16_f16(H1, B0, acc10, 0, 0, 0); \
  acc11 = __builtin_amdgcn_mfma_f32_32x32x16_f16(H1, B1, acc11, 0, 0, 0); \
  acc00 = __builtin_amdgcn_mfma_f32_32x32x16_f16(H0, B2, acc00, 0, 0, 0); \
  acc01 = __builtin_amdgcn_mfma_f32_32x32x16_f16(H0, B3, acc01, 0, 0, 0); \
  acc10 = __builtin_amdgcn_mfma_f32_32x32x16_f16(H1, B2, acc10, 0, 0, 0); \
  acc11 = __builtin_amdgcn_mfma_f32_32x32x16_f16(H1, B3, acc11, 0, 0, 0); \
  acc00 = __builtin_amdgcn_mfma_f32_32x32x16_f16(L0, B0, acc00, 0, 0, 0); \
  acc01 = __builtin_amdgcn_mfma_f32_32x32x16_f16(L0, B1, acc01, 0, 0, 0); \
  acc10 = __builtin_amdgcn_mfma_f32_32x32x16_f16(L1, B0, acc10, 0, 0, 0); \
  acc11 = __builtin_amdgcn_mfma_f32_32x32x16_f16(L1, B1, acc11, 0, 0, 0); \
  __builtin_amdgcn_s_setprio(0);

  auto run_layer = [&](const _Float16* __restrict__ wh,
                       const _Float16* __restrict__ wl) {
    acc00 = (f32x16)(0.f);
    acc01 = (f32x16)(0.f);
    acc10 = (f32x16)(0.f);
    acc11 = (f32x16)(0.f);
    half8 A0H0, A0L0, A0H1, A0L1, A1H0, A1L0, A1H1, A1L1;
    half8 S0B0, S0B1, S0B2, S0B3, S1B0, S1B1, S1B2, S1B3;
    LDA(A0H0, A0L0, A0H1, A0L1, 0)
    LDB(S0B0, S0B1, S0B2, S0B3, 0)
    // even k consume slot0, odd consume slot1; load k+1 into other slot
    LDA(A1H0, A1L0, A1H1, A1L1, 1)  LDB(S1B0, S1B1, S1B2, S1B3, 1)  MM(A0H0, A0L0, A0H1, A0L1, S0B0, S0B1, S0B2, S0B3)   // 0
    LDA(A0H0, A0L0, A0H1, A0L1, 2)  LDB(S0B0, S0B1, S0B2, S0B3, 2)  MM(A1H0, A1L0, A1H1, A1L1, S1B0, S1B1, S1B2, S1B3)   // 1
    LDA(A1H0, A1L0, A1H1, A1L1, 3)  LDB(S1B0, S1B1, S1B2, S1B3, 3)  MM(A0H0, A0L0, A0H1, A0L1, S0B0, S0B1, S0B2, S0B3)   // 2
    LDA(A0H0, A0L0, A0H1, A0L1, 4)  LDB(S0B0, S0B1, S0B2, S0B3, 4)  MM(A1H0, A1L0, A1H1, A1L1, S1B0, S1B1, S1B2, S1B3)   // 3
    LDA(A1H0, A1L0, A1H1, A1L1, 5)  LDB(S1B0, S1B1, S1B2, S1B3, 5)  MM(A0H0, A0L0, A0H1, A0L1, S0B0, S0B1, S0B2, S0B3)   // 4
    LDA(A0H0, A0L0, A0H1, A0L1, 6)  LDB(S0B0, S0B1, S0B2, S0B3, 6)  MM(A1H0, A1L0, A1H1, A1L1, S1B0, S1B1, S1B2, S1B3)   // 5
    LDA(A1H0, A1L0, A1H1, A1L1, 7)  LDB(S1B0, S1B1, S1B2, S1B3, 7)  MM(A0H0, A0L0, A0H1, A0L1, S0B0, S0B1, S0B2, S0B3)   // 6
    LDA(A0H0, A0L0, A0H1, A0L1, 8)  LDB(S0B0, S0B1, S0B2, S0B3, 8)  MM(A1H0, A1L0, A1H1, A1L1, S1B0, S1B1, S1B2, S1B3)   // 7
    LDA(A1H0, A1L0, A1H1, A1L1, 9)  LDB(S1B0, S1B1, S1B2, S1B3, 9)  MM(A0H0, A0L0, A0H1, A0L1, S0B0, S0B1, S0B2, S0B3)   // 8
    LDA(A0H0, A0L0, A0H1, A0L1, 10) LDB(S0B0, S0B1, S0B2, S0B3, 10) MM(A1H0, A1L0, A1H1, A1L1, S1B0, S1B1, S1B2, S1B3)   // 9
    LDA(A1H0, A1L0, A1H1, A1L1, 11) LDB(S1B0, S1B1, S1B2, S1B3, 11) MM(A0H0, A0L0, A0H1, A0L1, S0B0, S0B1, S0B2, S0B3)   // 10
    LDA(A0H0, A0L0, A0H1, A0L1, 12) LDB(S0B0, S0B1, S0B2, S0B3, 12) MM(A1H0, A1L0, A1H1, A1L1, S1B0, S1B1, S1B2, S1B3)   // 11
    LDA(A1H0, A1L0, A1H1, A1L1, 13) LDB(S1B0, S1B1, S1B2, S1B3, 13) MM(A0H0, A0L0, A0H1, A0L1, S0B0, S0B1, S0B2, S0B3)   // 12
    LDA(A0H0, A0L0, A0H1, A0L1, 14) LDB(S0B0, S0B1, S0B2, S0B3, 14) MM(A1H0, A1L0, A1H1, A1L1, S1B0, S1B1, S1B2, S1B3)   // 13
    LDA(A1H0, A1L0, A1H1, A1L1, 15) LDB(S1B0, S1B1, S1B2, S1B3, 15) MM(A0H0, A0L0, A0H1, A0L1, S0B0, S0B1, S0B2, S0B3)   // 14
                                                                    MM(A1H0, A1L0, A1H1, A1L1, S1B0, S1B1, S1B2, S1B3)   // 15
  };

  // ---- layer 1 ----
  run_layer(wt1hi, wt1lo);
  __syncthreads();   // all waves done reading h0
  {
#pragma unroll
    for (int jt = 0; jt < 2; ++jt) {
#pragma unroll
      for (int q = 0; q < 4; ++q) {
        const int jq = 64 * w + 32 * jt + 8 * q + 4 * kh;
        const float4 bb = *(const float4*)(b1 + node * H_ + jq);
        const float bv[4] = {bb.x, bb.y, bb.z, bb.w};
        const int soff = ((((8 * w + 4 * jt + q) ^ lc) << 4) + (kh << 3));
        half4v hv, lv;
#pragma unroll
        for (int r = 0; r < 4; ++r) {
          const float v = fmaxf((jt == 0 ? acc00[4 * q + r] : acc10[4 * q + r]) + bv[r], 0.f);
          const _Float16 h16 = (_Float16)v;
          hv[r] = h16;
          lv[r] = (_Float16)(v - (float)h16);
        }
        *(half4v*)((char*)h_hi + lc * 512 + soff) = hv;
        *(half4v*)((char*)h_lo + lc * 512 + soff) = lv;
#pragma unroll
        for (int r = 0; r < 4; ++r) {
          const float v = fmaxf((jt == 0 ? acc01[4 * q + r] : acc11[4 * q + r]) + bv[r], 0.f);
          const _Float16 h16 = (_Float16)v;
          hv[r] = h16;
          lv[r] = (_Float16)(v - (float)h16);
        }
        *(half4v*)((char*)h_hi + (32 + lc) * 512 + soff) = hv;
        *(half4v*)((char*)h_lo + (32 + lc) * 512 + soff) = lv;
      }
    }
  }
  __syncthreads();

  // ---- layer 2 + fused Wout ----
  run_layer(wt2hi, wt2lo);
  {
    float s0 = 0.f, s1 = 0.f;
#pragma unroll
    for (int jt = 0; jt < 2; ++jt) {
#pragma unroll
      for (int q = 0; q < 4; ++q) {
        const int jq = 64 * w + 32 * jt + 8 * q + 4 * kh;
        const float4 bb = *(const float4*)(b2 + node * H_ + jq);
        const float4 wo = *(const float4*)(Wout + node * H_ + jq);
        const float bv[4] = {bb.x, bb.y, bb.z, bb.w};
        const float wv[4] = {wo.x, wo.y, wo.z, wo.w};
#pragma unroll
        for (int r = 0; r < 4; ++r) {
          const float a0v = (jt == 0 ? acc00[4 * q + r] : acc10[4 * q + r]);
          const float a1v = (jt == 0 ? acc01[4 * q + r] : acc11[4 * q + r]);
          s0 = fmaf(fmaxf(a0v + bv[r], 0.f), wv[r], s0);
          s1 = fmaf(fmaxf(a1v + bv[r], 0.f), wv[r], s1);
        }
      }
    }
    s0 += __shfl_xor(s0, 32, 64);   // combine kh halves (same m)
    s1 += __shfl_xor(s1, 32, 64);
    if (lane < 32) {
      atomicAdd(&predpart[lc], s0);
      atomicAdd(&predpart[32 + lc], s1);
    }
  }
  __syncthreads();

  if (tid < MT)
    pred[(size_t)node * (B_ * P_) + p0 + tid] =
        wgt[tid] * (predpart[tid] + bout[node] + 0.5f);
}

// ---------------------------------------------------------------------------
// finalize: ldif = sum over nodes of pred[n][point]; sigmoid output.
// ---------------------------------------------------------------------------
__global__ void finalize(const float* __restrict__ pred, float* __restrict__ out) {
  const int i = blockIdx.x * 256 + threadIdx.x;
  float v = 0.f;
#pragma unroll
  for (int n = 0; n < N_; ++n) v += pred[n * (B_ * P_) + i];
  out[i] = v;
  const float zz = 100.0f * (-0.07f - v);
  out[B_ * P_ + i] = 1.0f / (1.0f + expf(-zz));
}

// ---------------------------------------------------------------------------
extern "C" void kernel_launch(void* const* d_in, const int* in_sizes, int n_in,
                              void* d_out, int out_size, void* d_ws, size_t ws_size,
                              hipStream_t stream) {
  const float* X = (const float*)d_in[0];
  const float* latents = (const float*)d_in[1];
  const float* constants = (const float*)d_in[2];
  const float* scales = (const float*)d_in[3];
  const float* rotations = (const float*)d_in[4];
  const float* centers = (const float*)d_in[5];
  const float* W0 = (const float*)d_in[6];
  const float* b0 = (const float*)d_in[7];
  const float* W1 = (const float*)d_in[8];
  const float* b1 = (const float*)d_in[9];
  const float* W2 = (const float*)d_in[10];
  const float* b2 = (const float*)d_in[11];
  const float* Wout = (const float*)d_in[12];
  const float* bout = (const float*)d_in[13];
  const int* use_constants = (const int*)d_in[14];

  float* pred = (float*)d_ws;                        // N*B*P f32 (1 MB)
  float* Zbuf = pred + (size_t)N_ * B_ * P_;         // B*N*H f32 (256 KB)
  _Float16* WThi = (_Float16*)(Zbuf + B_ * N_ * H_); // 8 MB
  _Float16* WTlo = WThi + (size_t)2 * N_ * H_ * H_;  // 8 MB

  prep<<<dim3(N_ * B_ + N_ * 2 * 16), 256, 0, stream>>>(
      latents, W0, b0, W1, W2, Zbuf, WThi, WTlo);

  mlp_main<<<dim3(B_ * P_ / MT * N_), 256, 0, stream>>>(
      X, constants, scales, rotations, centers, W0, b1, b2, Wout, bout,
      Zbuf, WThi, WTlo, use_constants, pred);

  finalize<<<dim3(B_ * P_ / 256), 256, 0, stream>>>(pred, (float*)d_out);
}